// Round 1
// baseline (123.690 us; speedup 1.0000x reference)
//
#include <hip/hip_runtime.h>
#include <math.h>

#define BATCH   64
#define SEQ     8192
#define NHEAD   8
#define HIDDEN  256
#define CHUNKS  16
#define TCHUNK  512                     // SEQ / CHUNKS
#define SCALE   0.17677669529663687f    // 1/sqrt(32)

// ws layout (floats):
//   alpha  [0,   512)
//   mval   [512, 1024)
//   rz     [1024,1536)
//   partial[1536, 1536 + 64*16*256)
#define WS_ALPHA   0
#define WS_M       512
#define WS_RZ      1024
#define WS_PARTIAL 1536

// ---------------------------------------------------------------- kernel 1
// Compute alpha[b,h] = SCALE * (x[b,0]*A_h + C_h),
//   A_h = sum_{d in head} qw*kw, C_h = sum_{d in head} qb*kw
__global__ void prep_kernel(const float* __restrict__ x,
                            const float* __restrict__ qw,
                            const float* __restrict__ qb,
                            const float* __restrict__ kw,
                            float* __restrict__ ws) {
    __shared__ float sA[NHEAD], sC[NHEAD];
    int tid = threadIdx.x;
    if (tid < 128) {
        float p1 = qw[tid] * kw[tid];
        float p2 = qb[tid] * kw[tid];
        // reduce within groups of 16 lanes (contiguous inside a wave)
        #pragma unroll
        for (int msk = 1; msk < 16; msk <<= 1) {
            p1 += __shfl_xor(p1, msk);
            p2 += __shfl_xor(p2, msk);
        }
        if ((tid & 15) == 0) {
            sA[tid >> 4] = p1;
            sC[tid >> 4] = p2;
        }
    }
    __syncthreads();
    if (tid < BATCH * NHEAD) {
        int b = tid >> 3;
        int h = tid & 7;
        float x0 = x[(size_t)b * SEQ];
        ws[WS_ALPHA + tid] = SCALE * (x0 * sA[h] + sC[h]);
    }
}

// ---------------------------------------------------------------- kernel 2
// Per (b,h): m = max_t alpha*x_t ; Z = sum_t exp(alpha*x_t - m); store m, 1/Z
__global__ void stats_kernel(const float* __restrict__ x,
                             float* __restrict__ ws) {
    __shared__ float sm[4];
    int bid = blockIdx.x;              // 0..511
    int b   = bid >> 3;
    int tid = threadIdx.x;             // 256 threads
    float a = ws[WS_ALPHA + bid];
    const float* xb = x + (size_t)b * SEQ;

    // pass 1: max of a*x
    float lm = -INFINITY;
    for (int i = tid; i < SEQ; i += 256)
        lm = fmaxf(lm, a * xb[i]);
    #pragma unroll
    for (int msk = 32; msk >= 1; msk >>= 1)
        lm = fmaxf(lm, __shfl_xor(lm, msk));
    if ((tid & 63) == 0) sm[tid >> 6] = lm;
    __syncthreads();
    float m = fmaxf(fmaxf(sm[0], sm[1]), fmaxf(sm[2], sm[3]));
    __syncthreads();

    // pass 2: Z = sum exp(a*x - m)
    float ls = 0.f;
    for (int i = tid; i < SEQ; i += 256)
        ls += __expf(a * xb[i] - m) ;
    #pragma unroll
    for (int msk = 32; msk >= 1; msk >>= 1)
        ls += __shfl_xor(ls, msk);
    if ((tid & 63) == 0) sm[tid >> 6] = ls;
    __syncthreads();
    if (tid == 0) {
        float Z = sm[0] + sm[1] + sm[2] + sm[3];
        ws[WS_M  + bid] = m;
        ws[WS_RZ + bid] = 1.f / Z;
    }
}

// ---------------------------------------------------------------- kernel 3
// Partial context: for chunk of 512 t-rows, each thread owns column c:
//   partial[b][chunk][c] = sum_t coeff[t][c/32] * G[t0+t][c]
// where coeff[t][h] = exp(alpha*x_t - m)/Z * x_t
__global__ void contract_kernel(const float* __restrict__ x,
                                const float* __restrict__ G,
                                float* __restrict__ ws) {
    __shared__ float coeff[TCHUNK * NHEAD];   // 16 KB
    __shared__ float sal[NHEAD], smm[NHEAD], srz[NHEAD];
    int chunk = blockIdx.x;   // 0..15
    int b     = blockIdx.y;   // 0..63
    int tid   = threadIdx.x;  // 0..255
    int t0    = chunk * TCHUNK;

    if (tid < NHEAD) {
        sal[tid] = ws[WS_ALPHA + b * NHEAD + tid];
        smm[tid] = ws[WS_M     + b * NHEAD + tid];
        srz[tid] = ws[WS_RZ    + b * NHEAD + tid];
    }
    __syncthreads();

    const float* xb = x + (size_t)b * SEQ + t0;
    // compute coefficients: 4096 values, 16 per thread
    for (int k = tid; k < TCHUNK * NHEAD; k += 256) {
        int t = k >> 3;
        int h = k & 7;
        float e = xb[t];
        coeff[k] = __expf(sal[h] * e - smm[h]) * srz[h] * e;
    }
    __syncthreads();

    int h = tid >> 5;                      // head of this column
    const float* gp = G + (size_t)t0 * HIDDEN + tid;
    float acc = 0.f;
    #pragma unroll 4
    for (int t = 0; t < TCHUNK; ++t) {
        acc = fmaf(coeff[(t << 3) + h], gp[(size_t)t * HIDDEN], acc);
    }
    ws[WS_PARTIAL + ((size_t)b * CHUNKS + chunk) * HIDDEN + tid] = acc;
}

// ---------------------------------------------------------------- kernel 4
// Sum partials per (b,c), then 256-element descending bitonic sort per b.
__global__ void reduce_sort_kernel(const float* __restrict__ ws,
                                   float* __restrict__ out) {
    __shared__ float v[HIDDEN];
    int b   = blockIdx.x;
    int tid = threadIdx.x;
    float s = 0.f;
    #pragma unroll
    for (int ch = 0; ch < CHUNKS; ++ch)
        s += ws[WS_PARTIAL + ((size_t)b * CHUNKS + ch) * HIDDEN + tid];
    v[tid] = s;
    __syncthreads();

    // bitonic sort, descending
    for (int k = 2; k <= HIDDEN; k <<= 1) {
        for (int j = k >> 1; j > 0; j >>= 1) {
            int ixj = tid ^ j;
            if (ixj > tid) {
                float a  = v[tid];
                float bb = v[ixj];
                bool up  = (tid & k) == 0;          // descending run
                if (up ? (a < bb) : (a > bb)) {
                    v[tid] = bb;
                    v[ixj] = a;
                }
            }
            __syncthreads();
        }
    }
    out[(size_t)b * HIDDEN + tid] = v[tid];
}

// ---------------------------------------------------------------- launcher
extern "C" void kernel_launch(void* const* d_in, const int* in_sizes, int n_in,
                              void* d_out, int out_size, void* d_ws, size_t ws_size,
                              hipStream_t stream) {
    const float* x  = (const float*)d_in[0];   // (64, 8192, 1)
    const float* qw = (const float*)d_in[1];   // (128,1)
    const float* qb = (const float*)d_in[2];   // (128,)
    const float* kw = (const float*)d_in[3];   // (128,1)
    // d_in[4] = k_b (cancels in softmax), d_in[5] = gaussian_basis
    const float* G  = (const float*)d_in[5];   // (8192, 256)
    float* out = (float*)d_out;
    float* ws  = (float*)d_ws;

    prep_kernel<<<1, 512, 0, stream>>>(x, qw, qb, kw, ws);
    stats_kernel<<<BATCH * NHEAD, 256, 0, stream>>>(x, ws);
    contract_kernel<<<dim3(CHUNKS, BATCH), 256, 0, stream>>>(x, G, ws);
    reduce_sort_kernel<<<BATCH, 256, 0, stream>>>(ws, out);
}